// Round 2
// baseline (214.761 us; speedup 1.0000x reference)
//
#include <hip/hip_runtime.h>
#include <hip/hip_bf16.h>

// out[u, d] = sum_k user_matrix[u, k] * features[user_graph[u, k], d]
// U = 1,000,000, K = 10, D = 32.
// Harness delivers integer inputs as int32 (per contract), so user_graph is
// const int*, NOT long long, even though the reference uses int64.
// Layout: 8 lanes per user; lane r owns float4 columns [4r, 4r+4).
// Each gather of a feature row is 8 lanes x 16 B = 128 B coalesced.

#define U_COUNT 1000000
#define K_NBR   10
#define D_DIM   32

__global__ __launch_bounds__(256) void user_graph_gather_kernel(
    const float* __restrict__ features,   // [U, 32] f32
    const int*   __restrict__ user_graph, // [U, 10] i32 (harness-converted)
    const float* __restrict__ user_matrix,// [U, 10] f32
    float* __restrict__ out)              // [U, 32] f32
{
    int t = blockIdx.x * blockDim.x + threadIdx.x;   // 8M threads
    int u = t >> 3;          // user id
    int r = t & 7;           // float4 slot within the 32-float row
    if (u >= U_COUNT) return;

    const int*   gu = user_graph + (long long)u * K_NBR;
    const float* wu = user_matrix + (long long)u * K_NBR;

    // Prefetch all indices + weights into registers so the 10 dependent
    // row-gathers can issue back-to-back.
    int   idx[K_NBR];
    float wk[K_NBR];
#pragma unroll
    for (int k = 0; k < K_NBR; ++k) {
        idx[k] = gu[k];
        wk[k]  = wu[k];
    }

    float4 acc = make_float4(0.f, 0.f, 0.f, 0.f);
#pragma unroll
    for (int k = 0; k < K_NBR; ++k) {
        const float4* row = reinterpret_cast<const float4*>(
            features + (long long)idx[k] * D_DIM);
        float4 v = row[r];
        float w = wk[k];
        acc.x += w * v.x;
        acc.y += w * v.y;
        acc.z += w * v.z;
        acc.w += w * v.w;
    }

    reinterpret_cast<float4*>(out)[(long long)u * 8 + r] = acc;
}

extern "C" void kernel_launch(void* const* d_in, const int* in_sizes, int n_in,
                              void* d_out, int out_size, void* d_ws, size_t ws_size,
                              hipStream_t stream) {
    const float* features    = (const float*)d_in[0];  // 32M f32
    const int*   user_graph  = (const int*)d_in[1];    // 10M i32
    const float* user_matrix = (const float*)d_in[2];  // 10M f32
    float*       out         = (float*)d_out;          // 32M f32

    const int total_threads = U_COUNT * 8;        // 8,000,000
    const int block = 256;
    const int grid  = (total_threads + block - 1) / block;  // 31250

    user_graph_gather_kernel<<<grid, block, 0, stream>>>(
        features, user_graph, user_matrix, out);
}

// Round 4
// 213.248 us; speedup vs baseline: 1.0071x; 1.0071x over previous
//
#include <hip/hip_runtime.h>
#include <hip/hip_bf16.h>

// out[u, d] = sum_k user_matrix[u, k] * features[user_graph[u, k], d]
// U = 1,000,000, K = 10, D = 32.
//
// Mapping: 8 lanes per user; lane r owns float4 columns [4r, 4r+4).
// Each feature-row gather = 8 lanes x 16 B = one aligned 128 B cache line.
//
// Non-temporal hints on the single-use streams (graph, weights, output) so
// L2 capacity is reserved for the 128 MB feature table (~10x reuse).
// Native clang vector type used because __builtin_nontemporal_* rejects
// HIP_vector_type structs.

#define U_COUNT 1000000
#define K_NBR   10
#define D_DIM   32

typedef float f32x4 __attribute__((ext_vector_type(4)));

__global__ __launch_bounds__(256) void user_graph_gather_kernel(
    const float* __restrict__ features,   // [U, 32] f32  (reused -> cache)
    const int*   __restrict__ user_graph, // [U, 10] i32  (streamed -> nt)
    const float* __restrict__ user_matrix,// [U, 10] f32  (streamed -> nt)
    float* __restrict__ out)              // [U, 32] f32  (streamed -> nt)
{
    int t = blockIdx.x * blockDim.x + threadIdx.x;   // 8M threads
    int u = t >> 3;          // user id
    int r = t & 7;           // float4 slot within the 32-float row
    if (u >= U_COUNT) return;

    const int*   gu = user_graph + (long long)u * K_NBR;
    const float* wu = user_matrix + (long long)u * K_NBR;

    // Prefetch indices + weights into registers (non-temporal: single use).
    int   idx[K_NBR];
    float wk[K_NBR];
#pragma unroll
    for (int k = 0; k < K_NBR; ++k) {
        idx[k] = __builtin_nontemporal_load(gu + k);
        wk[k]  = __builtin_nontemporal_load(wu + k);
    }

    f32x4 acc = (f32x4)(0.f);
#pragma unroll
    for (int k = 0; k < K_NBR; ++k) {
        const f32x4* row = reinterpret_cast<const f32x4*>(
            features + (long long)idx[k] * D_DIM);
        f32x4 v = row[r];           // cached: feature table has ~10x reuse
        acc += wk[k] * v;
    }

    f32x4* op = reinterpret_cast<f32x4*>(out) + ((long long)u * 8 + r);
    __builtin_nontemporal_store(acc, op);
}

extern "C" void kernel_launch(void* const* d_in, const int* in_sizes, int n_in,
                              void* d_out, int out_size, void* d_ws, size_t ws_size,
                              hipStream_t stream) {
    const float* features    = (const float*)d_in[0];  // 32M f32
    const int*   user_graph  = (const int*)d_in[1];    // 10M i32
    const float* user_matrix = (const float*)d_in[2];  // 10M f32
    float*       out         = (float*)d_out;          // 32M f32

    const int total_threads = U_COUNT * 8;        // 8,000,000
    const int block = 256;
    const int grid  = (total_threads + block - 1) / block;  // 31250

    user_graph_gather_kernel<<<grid, block, 0, stream>>>(
        features, user_graph, user_matrix, out);
}